// Round 6
// baseline (476.913 us; speedup 1.0000x reference)
//
#include <hip/hip_runtime.h>
#include <cstdint>
#include <cstddef>

// Problem constants (B=4, V=64, E=1024, L=1024, D=256, DEG=16)
constexpr int Bv = 4;
constexpr int Ev = 1024;      // edges per batch
constexpr int Lv = 1024;
constexpr int BE = Bv * Ev;   // 4096
constexpr size_t EI_PLANE = (size_t)BE * Lv;  // 4,194,304 elements per ei plane

// bf16 LDS row stride for hs tile: 256 + 8 pad -> 528 B rows (16B aligned;
// b128 fragment reads land 2-way on banks = free)
constexpr int STRB = 264;
// l's per block (multi-l pipeline)
constexpr int NL = 8;

typedef __bf16 bf16x8 __attribute__((ext_vector_type(8)));
typedef __bf16 bf16x4 __attribute__((ext_vector_type(4)));
typedef __bf16 bf16x2 __attribute__((ext_vector_type(2)));
typedef float  f32x4  __attribute__((ext_vector_type(4)));

// pack two f32 -> one dword of 2 bf16 (RNE, compiler emits v_cvt_pk_bf16_f32)
static __device__ __forceinline__ unsigned int pack_bf2(float lo, float hi) {
    union { bf16x2 h; unsigned int u; } c;
    c.h[0] = (__bf16)lo; c.h[1] = (__bf16)hi;
    return c.u;
}

// ---------------------------------------------------------------------------
// Precompute (grid 257 x 256 threads):
//  blocks 0..255: tile (i = blk>>4, j = blk&15) of M' = (Wq^T Wk) / 16,
//    bf16, written pre-swizzled to MFMA fragment layout (A- and B-fragment
//    layouts are identical for 16x16x32):
//      for element (d, t):  f = (d>>5)*16 + (t>>4);
//                           lane = ((d>>3)&3)*16 + (t&15); jj = d&7;
//      Mb[(f*64 + lane)*8 + jj] = M'[d][t]
//  block 256: rv[t] = (sum_i bq[i] * Wk[i*256+t]) / 16  (fp32)
//  (bk and the h_src-only bias terms cancel in the softmax -> never computed;
//   the 1/sqrt(D)=1/16 logit scale is folded in here.)
// ---------------------------------------------------------------------------
__global__ __launch_bounds__(256) void precompute_kernel(
    const float* __restrict__ Wq, const float* __restrict__ Wk,
    const float* __restrict__ bq, __bf16* __restrict__ Mb, float* __restrict__ rv)
{
    const int blk = blockIdx.x;
    const int tid = threadIdx.x;
    if (blk < 256) {
        __shared__ float qs[256 * 17];
        __shared__ float ks[256 * 17];
        const int i16 = (blk >> 4) * 16;   // d-tile base
        const int j16 = (blk & 15) * 16;   // t-tile base
        const int c  = tid & 15;
        const int r0 = tid >> 4;
        #pragma unroll
        for (int it = 0; it < 16; ++it) {
            const int r = it * 16 + r0;
            qs[r * 17 + c] = Wq[r * 256 + i16 + c];
            ks[r * 17 + c] = Wk[r * 256 + j16 + c];
        }
        __syncthreads();
        const int dd = tid >> 4;   // 0..15 local d
        const int tt = tid & 15;   // 0..15 local t
        float a0 = 0.f, a1 = 0.f, a2 = 0.f, a3 = 0.f;
        for (int r = 0; r < 256; r += 4) {
            a0 = fmaf(qs[(r + 0) * 17 + dd], ks[(r + 0) * 17 + tt], a0);
            a1 = fmaf(qs[(r + 1) * 17 + dd], ks[(r + 1) * 17 + tt], a1);
            a2 = fmaf(qs[(r + 2) * 17 + dd], ks[(r + 2) * 17 + tt], a2);
            a3 = fmaf(qs[(r + 3) * 17 + dd], ks[(r + 3) * 17 + tt], a3);
        }
        const float m = ((a0 + a1) + (a2 + a3)) * 0.0625f;
        const int d = i16 + dd, t = j16 + tt;
        const int f    = (d >> 5) * 16 + (t >> 4);
        const int lane = ((d >> 3) & 3) * 16 + (t & 15);
        const int jj   = d & 7;
        Mb[((size_t)f * 64 + lane) * 8 + jj] = (__bf16)m;
    } else {
        __shared__ float bqs[256];
        bqs[tid] = bq[tid];
        __syncthreads();
        float a0 = 0.f, a1 = 0.f;
        for (int i = 0; i < 256; i += 2) {
            a0 = fmaf(bqs[i + 0], Wk[(i + 0) * 256 + tid], a0);
            a1 = fmaf(bqs[i + 1], Wk[(i + 1) * 256 + tid], a1);
        }
        rv[tid] = (a0 + a1) * 0.0625f;
    }
}

// ---------------------------------------------------------------------------
// Main fused kernel, multi-l pipelined (T14 issue-early / write-late).
// Grid 512 blocks; block (b, l0) handles l = l0 .. l0+NL-1.
// LDS = 2 x hs tile (67584 B) -> 2 blocks/CU (all 512 resident).
// Per l:
//   1) issue next-l's 16 float4 global loads into registers (issue-early)
//   2) compute from buf[cur] with R5's 2x2 wave ownership:
//      wave w: vgrp=w>>1 owns S rows [32*vgrp,+32); thalf=w&1 owns t-half.
//      GEMM1 swapped (Mb-frag x hs-frag) -> reg T^T; cvt_pk + permlane
//      route -> GEMM2 A-frag; band-S partial (dst in src+1..+16 mod 64).
//   3) barrier; two-pass S combine on overlay of buf[cur]; barrier x2
//   4) logits + group-of-16 softmax; probs write
//   5) vmcnt drain; cvt; ds_write next-l into buf[cur^1] (write-late); barrier
// Staging HBM latency (~900 cyc) hides under compute+softmax (~2500 cyc).
// ---------------------------------------------------------------------------
template <bool USE_WS>
__global__ __launch_bounds__(256, 2) void edge_main(
    const float* __restrict__ hs, const int* __restrict__ eidx,
    const float* __restrict__ ew, const float* __restrict__ skipp,
    const __bf16* __restrict__ Mb, const float* __restrict__ rv,
    float* __restrict__ probs_or_out)
{
    __shared__ __bf16 hs2_s[2][64 * STRB];      // 67584 B total

    const int blk = blockIdx.x;         // 0..511
    const int b   = blk >> 7;           // 128 blocks per batch
    const int l0  = (blk & 127) * NL;
    const int tid  = threadIdx.x;
    const int w    = tid >> 6;          // wave 0..3
    const int lane = tid & 63;
    const int l15  = lane & 15;
    const int quad = lane >> 4;
    const int vgrp  = w >> 1;           // S row group (rows 32*vgrp ..)
    const int thalf = w & 1;            // t half (t = thalf*128 ..)
    const int vt0   = vgrp * 2;         // first owned v-tile (0 or 2)
    const int half  = lane >> 5;        // staging: 0..1
    const int c8    = (lane & 31) * 8;  // staging col base

    const float* hb = hs + (size_t)b * 65536 * 256;   // batch base (64*1024 rows)

    // ---- hoisted per-edge indices (same for every l of this block) ----
    const int e0  = tid * 4;
    const int be0 = b * Ev + e0;
    int soff[4];
    #pragma unroll
    for (int j = 0; j < 4; ++j) {
        const int src = eidx[be0 + j];
        const int dst = eidx[BE + be0 + j];
        // dst in {src+1..src+16} mod 64 -> slot in {0,1} always
        const int slot = ((dst >> 4) - (src >> 4)) & 3;
        soff[j] = src * 36 + slot * 16 + (dst & 15);
    }

    // ---- prologue: stage l0 into buf 0 ----
    {
        const float* base = hb + (size_t)l0 * 256;
        #pragma unroll
        for (int k = 0; k < 8; ++k) {
            const int v = k * 8 + w * 2 + half;
            const float* p = base + (size_t)v * (1024 * 256) + c8;
            float4 va = *(const float4*)p;
            float4 vb = *(const float4*)(p + 4);
            bf16x8 h;
            h[0] = (__bf16)va.x; h[1] = (__bf16)va.y;
            h[2] = (__bf16)va.z; h[3] = (__bf16)va.w;
            h[4] = (__bf16)vb.x; h[5] = (__bf16)vb.y;
            h[6] = (__bf16)vb.z; h[7] = (__bf16)vb.w;
            *(bf16x8*)(&hs2_s[0][v * STRB + c8]) = h;
        }
    }
    __syncthreads();

    int cur = 0;
    #pragma unroll 1
    for (int i = 0; i < NL; ++i) {
        const int l = l0 + i;
        __bf16* bufc = &hs2_s[cur][0];
        float*  S0   = (float*)bufc;     // band-S 64 x 36 overlay (9216 B)

        // ---- 1) issue-early: next l's tile into registers ----
        // (unconditional, clamped: last iter re-reads l -- L2 hits, keeps
        //  the loads as straight-line early issue for the scheduler)
        const int lnext = (i + 1 < NL) ? (l + 1) : l;
        const float* basen = hb + (size_t)lnext * 256;
        float4 pf[16];
        #pragma unroll
        for (int k = 0; k < 8; ++k) {
            const float* p = basen + (size_t)(k * 8 + w * 2 + half) * (1024 * 256) + c8;
            pf[2 * k]     = *(const float4*)p;
            pf[2 * k + 1] = *(const float4*)(p + 4);
        }

        // ---- 2) compute: s_acc[mi][slot] band partials ----
        f32x4 s_acc[2][2];
        #pragma unroll
        for (int mi = 0; mi < 2; ++mi)
            #pragma unroll
            for (int sl = 0; sl < 2; ++sl) {
                s_acc[mi][sl][0] = 0.f; s_acc[mi][sl][1] = 0.f;
                s_acc[mi][sl][2] = 0.f; s_acc[mi][sl][3] = 0.f;
            }

        #pragma unroll 1
        for (int pp = 0; pp < 4; ++pp) {
            const int p = thalf * 4 + pp;    // t-tile pair index 0..7
            // GEMM1 (swapped): acc[tt][mi], t-tiles {2p, 2p+1} x v-tiles
            f32x4 acc[2][2];
            #pragma unroll
            for (int tt = 0; tt < 2; ++tt) {
                const f32x4 rb = *(const f32x4*)(rv + (2 * p + tt) * 16 + quad * 4);
                acc[tt][0] = rb;
                acc[tt][1] = rb;
            }
            #pragma unroll
            for (int kt = 0; kt < 8; ++kt) {
                const bf16x8 mfr0 = *(const bf16x8*)(Mb +
                    ((size_t)((kt * 16 + 2 * p + 0) * 64 + lane)) * 8);
                const bf16x8 mfr1 = *(const bf16x8*)(Mb +
                    ((size_t)((kt * 16 + 2 * p + 1) * 64 + lane)) * 8);
                #pragma unroll
                for (int mi = 0; mi < 2; ++mi) {
                    const bf16x8 hfr = *(const bf16x8*)(
                        &bufc[((vt0 + mi) * 16 + l15) * STRB + kt * 32 + quad * 8]);
                    acc[0][mi] = __builtin_amdgcn_mfma_f32_16x16x32_bf16(
                        mfr0, hfr, acc[0][mi], 0, 0, 0);
                    acc[1][mi] = __builtin_amdgcn_mfma_f32_16x16x32_bf16(
                        mfr1, hfr, acc[1][mi], 0, 0, 0);
                }
            }
            // pack + permlane route -> GEMM2 A-frag; band partial S
            #pragma unroll
            for (int mi = 0; mi < 2; ++mi) {
                const int m = vt0 + mi;
                unsigned int Ar = pack_bf2(acc[0][mi][0], acc[0][mi][1]);
                unsigned int Br = pack_bf2(acc[0][mi][2], acc[0][mi][3]);
                unsigned int Cr = pack_bf2(acc[1][mi][0], acc[1][mi][1]);
                unsigned int Dr = pack_bf2(acc[1][mi][2], acc[1][mi][3]);
                asm("v_permlane32_swap_b32 %0, %1" : "+v"(Ar), "+v"(Cr));
                asm("v_permlane16_swap_b32 %0, %1" : "+v"(Ar), "+v"(Cr));
                asm("v_permlane32_swap_b32 %0, %1" : "+v"(Br), "+v"(Dr));
                asm("v_permlane16_swap_b32 %0, %1" : "+v"(Br), "+v"(Dr));
                union { uint4 u; bf16x8 h; } fr;
                fr.u = make_uint4(Ar, Br, Cr, Dr);
                const bf16x8 brow0 = *(const bf16x8*)(
                    &bufc[(m * 16 + l15) * STRB + p * 32 + quad * 8]);
                const bf16x8 brow1 = *(const bf16x8*)(
                    &bufc[(((m + 1) & 3) * 16 + l15) * STRB + p * 32 + quad * 8]);
                s_acc[mi][0] = __builtin_amdgcn_mfma_f32_16x16x32_bf16(
                    fr.h, brow0, s_acc[mi][0], 0, 0, 0);
                s_acc[mi][1] = __builtin_amdgcn_mfma_f32_16x16x32_bf16(
                    fr.h, brow1, s_acc[mi][1], 0, 0, 0);
            }
        }
        __syncthreads();   // all waves done reading bufc -> reuse as S0

        // ---- 3) two-pass partial-S combine (rows disjoint by vgrp) ----
        if (!thalf) {      // waves 0,2: store their t-half partial
            #pragma unroll
            for (int mi = 0; mi < 2; ++mi)
                #pragma unroll
                for (int sl = 0; sl < 2; ++sl)
                    #pragma unroll
                    for (int r = 0; r < 4; ++r)
                        S0[((vt0 + mi) * 16 + quad * 4 + r) * 36 + sl * 16 + l15] =
                            s_acc[mi][sl][r];
        }
        __syncthreads();
        if (thalf) {       // waves 1,3: add their t-half partial
            #pragma unroll
            for (int mi = 0; mi < 2; ++mi)
                #pragma unroll
                for (int sl = 0; sl < 2; ++sl)
                    #pragma unroll
                    for (int r = 0; r < 4; ++r)
                        S0[((vt0 + mi) * 16 + quad * 4 + r) * 36 + sl * 16 + l15] +=
                            s_acc[mi][sl][r];
        }
        __syncthreads();

        // ---- 4) per-edge logits + group-of-16 softmax ----
        float lg[4];
        #pragma unroll
        for (int j = 0; j < 4; ++j)
            lg[j] = S0[soff[j]];

        float mx = fmaxf(fmaxf(lg[0], lg[1]), fmaxf(lg[2], lg[3]));
        mx = fmaxf(mx, __shfl_xor(mx, 1));
        mx = fmaxf(mx, __shfl_xor(mx, 2));
        float ex[4], sm = 0.f;
        #pragma unroll
        for (int j = 0; j < 4; ++j) { ex[j] = __expf(lg[j] - mx); sm += ex[j]; }
        sm += __shfl_xor(sm, 1);
        sm += __shfl_xor(sm, 2);
        const float inv = 1.0f / sm;

        if (USE_WS) {
            float4 o = make_float4(ex[0] * inv, ex[1] * inv, ex[2] * inv, ex[3] * inv);
            *(float4*)(probs_or_out + ((size_t)(b * 1024 + l)) * 1024 + e0) = o;
        } else {
            const float skip = skipp[0];
            const float om = 1.0f - skip;
            #pragma unroll
            for (int j = 0; j < 4; ++j) {
                float g = fmaf(skip, ew[be0 + j], om * (ex[j] * inv));
                probs_or_out[(size_t)(be0 + j) * Lv + l] = g;
            }
        }

        // ---- 5) write-late: staged tile -> buf[cur^1] ----
        // (targets the other buffer; S overlay lives on bufc -> disjoint.
        //  On the last iter this rewrites dead data -- harmless.)
        {
            __bf16* bufn = &hs2_s[cur ^ 1][0];
            #pragma unroll
            for (int k = 0; k < 8; ++k) {
                const int v = k * 8 + w * 2 + half;
                bf16x8 h;
                h[0] = (__bf16)pf[2 * k].x;     h[1] = (__bf16)pf[2 * k].y;
                h[2] = (__bf16)pf[2 * k].z;     h[3] = (__bf16)pf[2 * k].w;
                h[4] = (__bf16)pf[2 * k + 1].x; h[5] = (__bf16)pf[2 * k + 1].y;
                h[6] = (__bf16)pf[2 * k + 1].z; h[7] = (__bf16)pf[2 * k + 1].w;
                *(bf16x8*)(&bufn[v * STRB + c8]) = h;
            }
        }
        __syncthreads();   // staging visible + S reads done before next overlay
        cur ^= 1;
    }
}

// ---------------------------------------------------------------------------
// Output kernel: tiled transpose of probs (b,l,e) -> ew_out (be,l), plus ei
// broadcast. Block = (lt, et, b) transposes one 64x64 tile.
// ---------------------------------------------------------------------------
__global__ __launch_bounds__(256) void output_kernel(
    const float* __restrict__ probs, const int* __restrict__ eidx,
    const float* __restrict__ ew, const float* __restrict__ skipp,
    float* __restrict__ out)
{
    __shared__ float tile[64 * 68];
    const int lt = blockIdx.x;   // 0..15
    const int et = blockIdx.y;   // 0..15
    const int b  = blockIdx.z;   // 0..3
    const int t  = threadIdx.x;
    const int tr = t >> 4;       // 0..15
    const int tc = t & 15;       // 0..15

    #pragma unroll
    for (int q = 0; q < 4; ++q) {
        const int lloc = q * 16 + tr;
        float4 v = *(const float4*)(probs +
            ((size_t)(b * 1024 + lt * 64 + lloc)) * 1024 + et * 64 + tc * 4);
        *(float4*)(&tile[lloc * 68 + tc * 4]) = v;
    }
    __syncthreads();

    const float skip = skipp[0];
    const float om = 1.0f - skip;
    float* out_ei0 = out;
    float* out_ei1 = out + EI_PLANE;
    float* out_ew  = out + 2 * EI_PLANE;

    #pragma unroll
    for (int q = 0; q < 4; ++q) {
        const int eloc = q * 16 + tr;
        const int be = b * Ev + et * 64 + eloc;
        const float w  = ew[be];
        const float sv = (float)eidx[be];
        const float dv = (float)eidx[BE + be];
        const int lloc0 = tc * 4;
        float4 o;
        o.x = fmaf(skip, w, om * tile[(lloc0 + 0) * 68 + eloc]);
        o.y = fmaf(skip, w, om * tile[(lloc0 + 1) * 68 + eloc]);
        o.z = fmaf(skip, w, om * tile[(lloc0 + 2) * 68 + eloc]);
        o.w = fmaf(skip, w, om * tile[(lloc0 + 3) * 68 + eloc]);
        const size_t off = (size_t)be * Lv + lt * 64 + lloc0;
        *(float4*)(out_ew  + off) = o;
        *(float4*)(out_ei0 + off) = make_float4(sv, sv, sv, sv);
        *(float4*)(out_ei1 + off) = make_float4(dv, dv, dv, dv);
    }
}

// Fallback ei broadcast kernel (only used if ws too small for probs buffer)
__global__ __launch_bounds__(256) void ei_kernel(
    const int* __restrict__ eidx, float* __restrict__ out)
{
    const int blk = blockIdx.x;            // 0..8191  (c*4096 + j)
    const int c = blk >> 12;
    const int j = blk & 4095;
    const float v = (float)eidx[c * BE + j];
    float4 o = make_float4(v, v, v, v);
    *(float4*)(out + (size_t)blk * 1024 + threadIdx.x * 4) = o;
}

// ---------------------------------------------------------------------------
extern "C" void kernel_launch(void* const* d_in, const int* in_sizes, int n_in,
                              void* d_out, int out_size, void* d_ws, size_t ws_size,
                              hipStream_t stream)
{
    const float* hs   = (const float*)d_in[0];
    const int*   eidx = (const int*)d_in[1];
    const float* ew   = (const float*)d_in[2];
    const float* Wq   = (const float*)d_in[3];
    const float* bq   = (const float*)d_in[4];
    const float* Wk   = (const float*)d_in[5];
    // d_in[6] = bk: provably unused (cancels in softmax)
    const float* skip = (const float*)d_in[7];

    char* wsb = (char*)d_ws;
    __bf16* Mb   = (__bf16*)wsb;                       // 65536 bf16 = 128 KiB
    float*  rv   = (float*)(wsb + 131072);             // 256 fp32 = 1 KiB
    float*  probs = (float*)(wsb + 132096);            // 4M fp32 = 16 MiB
    const size_t need = 132096 + (size_t)Bv * Lv * Ev * sizeof(float);

    precompute_kernel<<<dim3(257), dim3(256), 0, stream>>>(Wq, Wk, bq, Mb, rv);

    if (ws_size >= need) {
        edge_main<true><<<dim3(Bv * Lv / NL), dim3(256), 0, stream>>>(
            hs, eidx, ew, skip, Mb, rv, probs);
        output_kernel<<<dim3(16, 16, 4), dim3(256), 0, stream>>>(
            probs, eidx, ew, skip, (float*)d_out);
    } else {
        float* out_ew = (float*)d_out + 2 * EI_PLANE;
        edge_main<false><<<dim3(Bv * Lv / NL), dim3(256), 0, stream>>>(
            hs, eidx, ew, skip, Mb, rv, out_ew);
        ei_kernel<<<dim3(2 * BE), dim3(256), 0, stream>>>(eidx, (float*)d_out);
    }
}

// Round 7
// 451.742 us; speedup vs baseline: 1.0557x; 1.0557x over previous
//
#include <hip/hip_runtime.h>
#include <cstdint>
#include <cstddef>

// Problem constants (B=4, V=64, E=1024, L=1024, D=256, DEG=16)
constexpr int Bv = 4;
constexpr int Ev = 1024;      // edges per batch
constexpr int Lv = 1024;
constexpr int BE = Bv * Ev;   // 4096
constexpr size_t EI_PLANE = (size_t)BE * Lv;  // 4,194,304 elements per ei plane

// bf16 LDS row stride for hs tile: 256 + 8 pad -> 528 B rows (16B aligned;
// b128 fragment reads land 2-way on banks = free)
constexpr int STRB = 264;

typedef __bf16 bf16x8 __attribute__((ext_vector_type(8)));
typedef __bf16 bf16x4 __attribute__((ext_vector_type(4)));
typedef __bf16 bf16x2 __attribute__((ext_vector_type(2)));
typedef float  f32x4  __attribute__((ext_vector_type(4)));

// pack two f32 -> one dword of 2 bf16 (RNE, compiler emits v_cvt_pk_bf16_f32)
static __device__ __forceinline__ unsigned int pack_bf2(float lo, float hi) {
    union { bf16x2 h; unsigned int u; } c;
    c.h[0] = (__bf16)lo; c.h[1] = (__bf16)hi;
    return c.u;
}

// ---------------------------------------------------------------------------
// Precompute (grid 257 x 256 threads):
//  blocks 0..255: tile (i = blk>>4, j = blk&15) of M' = (Wq^T Wk) / 16,
//    bf16, written pre-swizzled to MFMA fragment layout (A- and B-fragment
//    layouts are identical for 16x16x32):
//      for element (d, t):  f = (d>>5)*16 + (t>>4);
//                           lane = ((d>>3)&3)*16 + (t&15); jj = d&7;
//      Mb[(f*64 + lane)*8 + jj] = M'[d][t]
//  block 256: rv[t] = (sum_i bq[i] * Wk[i*256+t]) / 16  (fp32)
//  (bk and the h_src-only bias terms cancel in the softmax -> never computed;
//   the 1/sqrt(D)=1/16 logit scale is folded in here.)
// ---------------------------------------------------------------------------
__global__ __launch_bounds__(256) void precompute_kernel(
    const float* __restrict__ Wq, const float* __restrict__ Wk,
    const float* __restrict__ bq, __bf16* __restrict__ Mb, float* __restrict__ rv)
{
    const int blk = blockIdx.x;
    const int tid = threadIdx.x;
    if (blk < 256) {
        __shared__ float qs[256 * 17];
        __shared__ float ks[256 * 17];
        const int i16 = (blk >> 4) * 16;   // d-tile base
        const int j16 = (blk & 15) * 16;   // t-tile base
        const int c  = tid & 15;
        const int r0 = tid >> 4;
        #pragma unroll
        for (int it = 0; it < 16; ++it) {
            const int r = it * 16 + r0;
            qs[r * 17 + c] = Wq[r * 256 + i16 + c];
            ks[r * 17 + c] = Wk[r * 256 + j16 + c];
        }
        __syncthreads();
        const int dd = tid >> 4;   // 0..15 local d
        const int tt = tid & 15;   // 0..15 local t
        float a0 = 0.f, a1 = 0.f, a2 = 0.f, a3 = 0.f;
        for (int r = 0; r < 256; r += 4) {
            a0 = fmaf(qs[(r + 0) * 17 + dd], ks[(r + 0) * 17 + tt], a0);
            a1 = fmaf(qs[(r + 1) * 17 + dd], ks[(r + 1) * 17 + tt], a1);
            a2 = fmaf(qs[(r + 2) * 17 + dd], ks[(r + 2) * 17 + tt], a2);
            a3 = fmaf(qs[(r + 3) * 17 + dd], ks[(r + 3) * 17 + tt], a3);
        }
        const float m = ((a0 + a1) + (a2 + a3)) * 0.0625f;
        const int d = i16 + dd, t = j16 + tt;
        const int f    = (d >> 5) * 16 + (t >> 4);
        const int lane = ((d >> 3) & 3) * 16 + (t & 15);
        const int jj   = d & 7;
        Mb[((size_t)f * 64 + lane) * 8 + jj] = (__bf16)m;
    } else {
        __shared__ float bqs[256];
        bqs[tid] = bq[tid];
        __syncthreads();
        float a0 = 0.f, a1 = 0.f;
        for (int i = 0; i < 256; i += 2) {
            a0 = fmaf(bqs[i + 0], Wk[(i + 0) * 256 + tid], a0);
            a1 = fmaf(bqs[i + 1], Wk[(i + 1) * 256 + tid], a1);
        }
        rv[tid] = (a0 + a1) * 0.0625f;
    }
}

// ---------------------------------------------------------------------------
// Main fused kernel, v-split wave ownership. One block (4 waves) per (b,l).
// LDS = hs tile only (33792 B) -> 4 blocks/CU; __launch_bounds__(256,4)
// pins VGPR <= 128 (natural pressure ~110, kt batched in halves).
// Wave w owns v-tile w: computes S rows [16w, 16w+16) over ALL 256 t.
//  - All 4 waves read the SAME Mb fragments per pair -> L1/L2 broadcast
//    (t-split variants read disjoint slices: 4x the unique-line misses).
//  - hs fragments for the own v-tile persist in registers (hfrK[8], loaded
//    once): ds_reads drop ~80 -> ~17 per wave.
//  - Each wave's S rows are COMPLETE (all t contracted in-wave): the
//    cross-wave reduce is gone. 3 barriers total.
// Per t-pair p (t-tiles 2p, 2p+1):
//   GEMM1 swapped: acc[tt] = Mb-frag(t-tile) x hfrK -> lane holds col v,
//     rows t (16 MFMA); cvt_pk + permlane32/16 -> GEMM2 A-frag in regs;
//   GEMM2: s_acc[slot] += fr x brow(n-tile {w,(w+1)&3}, cols pair p)
//     (band: dst in src+1..src+16 mod 64): 2 MFMA.
// Then: barrier; store S rows (disjoint); barrier; logits + group-of-16
// softmax; probs write (or scattered ew_out if !USE_WS).
// ---------------------------------------------------------------------------
template <bool USE_WS>
__global__ __launch_bounds__(256, 4) void edge_main(
    const float* __restrict__ hs, const int* __restrict__ eidx,
    const float* __restrict__ ew, const float* __restrict__ skipp,
    const __bf16* __restrict__ Mb, const float* __restrict__ rv,
    float* __restrict__ probs_or_out)
{
    __shared__ __bf16 hs_s[64 * STRB];          // 33792 B (only LDS block)
    float* S0 = (float*)hs_s;                   // band-S 64 x 36 f32 overlay
    // (S0 only written after the post-GEMM2 barrier)

    const int bl = blockIdx.x;          // 0..4095
    const int b  = bl >> 10;
    const int l  = bl & 1023;
    const int tid  = threadIdx.x;
    const int w    = tid >> 6;          // wave 0..3 = owned v-tile
    const int lane = tid & 63;
    const int l15  = lane & 15;
    const int quad = lane >> 4;
    const int nt1  = (w + 1) & 3;       // band partner n-tile

    // ---- hoisted per-edge indices (overlap their latency with staging) ----
    const int e0  = tid * 4;
    const int be0 = b * Ev + e0;
    int soff[4];
    #pragma unroll
    for (int j = 0; j < 4; ++j) {
        const int src = eidx[be0 + j];
        const int dst = eidx[BE + be0 + j];
        // dst in {src+1..src+16} mod 64 -> slot in {0,1} always
        const int slot = ((dst >> 4) - (src >> 4)) & 3;
        soff[j] = src * 36 + slot * 16 + (dst & 15);
    }

    // ---- stage hs tile (64 rows x 256 cols fp32 -> bf16), coalesced ----
    {
        const float* base = hs + ((size_t)b * 64 * 1024 + (size_t)l) * 256;
        const int half = lane >> 5;          // 0..1
        const int c8   = (lane & 31) * 8;    // col base
        #pragma unroll
        for (int k = 0; k < 8; ++k) {
            const int v = k * 8 + w * 2 + half;
            const float* p = base + (size_t)v * (1024 * 256) + c8;
            float4 va = *(const float4*)p;
            float4 vb = *(const float4*)(p + 4);
            bf16x8 h;
            h[0] = (__bf16)va.x; h[1] = (__bf16)va.y;
            h[2] = (__bf16)va.z; h[3] = (__bf16)va.w;
            h[4] = (__bf16)vb.x; h[5] = (__bf16)vb.y;
            h[6] = (__bf16)vb.z; h[7] = (__bf16)vb.w;
            *(bf16x8*)(&hs_s[v * STRB + c8]) = h;
        }
    }
    __syncthreads();

    // ---- persistent hs fragments for own v-tile (8 x bf16x8 = 32 VGPR) ----
    bf16x8 hfrK[8];
    #pragma unroll
    for (int kt = 0; kt < 8; ++kt)
        hfrK[kt] = *(const bf16x8*)(&hs_s[(w * 16 + l15) * STRB + kt * 32 + quad * 8]);

    // s_acc[slot]: slot 0 -> n-tile w, slot 1 -> n-tile (w+1)&3  (8 VGPR)
    f32x4 s_acc0, s_acc1;
    s_acc0[0] = 0.f; s_acc0[1] = 0.f; s_acc0[2] = 0.f; s_acc0[3] = 0.f;
    s_acc1 = s_acc0;

    #pragma unroll 1
    for (int p = 0; p < 8; ++p) {
        // ---- GEMM1 (swapped): acc[tt] over t-tiles {2p, 2p+1} ----
        // bias rv[t] is per-ROW of T^T: element r gets rv[(2p+tt)*16+quad*4+r]
        f32x4 acc0 = *(const f32x4*)(rv + (2 * p + 0) * 16 + quad * 4);
        f32x4 acc1 = *(const f32x4*)(rv + (2 * p + 1) * 16 + quad * 4);
        #pragma unroll
        for (int kh = 0; kh < 2; ++kh) {
            // batch 8 Mb loads (shared addresses across ALL waves/blocks)
            bf16x8 m0[4], m1[4];
            #pragma unroll
            for (int k2 = 0; k2 < 4; ++k2) {
                const int kt = kh * 4 + k2;
                m0[k2] = *(const bf16x8*)(Mb +
                    ((size_t)((kt * 16 + 2 * p + 0) * 64 + lane)) * 8);
                m1[k2] = *(const bf16x8*)(Mb +
                    ((size_t)((kt * 16 + 2 * p + 1) * 64 + lane)) * 8);
            }
            #pragma unroll
            for (int k2 = 0; k2 < 4; ++k2) {
                const int kt = kh * 4 + k2;
                acc0 = __builtin_amdgcn_mfma_f32_16x16x32_bf16(
                    m0[k2], hfrK[kt], acc0, 0, 0, 0);
                acc1 = __builtin_amdgcn_mfma_f32_16x16x32_bf16(
                    m1[k2], hfrK[kt], acc1, 0, 0, 0);
            }
        }
        // ---- pack + permlane route -> GEMM2 A-frag (registers only) ----
        unsigned int Ar = pack_bf2(acc0[0], acc0[1]); // t = g*4+{0,1}
        unsigned int Br = pack_bf2(acc0[2], acc0[3]); // t = g*4+{2,3}
        unsigned int Cr = pack_bf2(acc1[0], acc1[1]); // t = 16+g*4+{0,1}
        unsigned int Dr = pack_bf2(acc1[2], acc1[3]); // t = 16+g*4+{2,3}
        asm("v_permlane32_swap_b32 %0, %1" : "+v"(Ar), "+v"(Cr));
        asm("v_permlane16_swap_b32 %0, %1" : "+v"(Ar), "+v"(Cr));
        asm("v_permlane32_swap_b32 %0, %1" : "+v"(Br), "+v"(Dr));
        asm("v_permlane16_swap_b32 %0, %1" : "+v"(Br), "+v"(Dr));
        union { uint4 u; bf16x8 h; } fr;
        fr.u = make_uint4(Ar, Br, Cr, Dr);   // A-frag, k = 32 t's of pair p

        // ---- GEMM2 band: S rows v-tile w, n-tiles {w, (w+1)&3} ----
        // (brow for n-tile w equals hfrK[p], but p is runtime here; reload
        //  from LDS to keep all register indices static -- rule #20.)
        const bf16x8 brow0 = *(const bf16x8*)(
            &hs_s[(w * 16 + l15) * STRB + p * 32 + quad * 8]);
        const bf16x8 brow1 = *(const bf16x8*)(
            &hs_s[(nt1 * 16 + l15) * STRB + p * 32 + quad * 8]);
        s_acc0 = __builtin_amdgcn_mfma_f32_16x16x32_bf16(fr.h, brow0, s_acc0, 0, 0, 0);
        s_acc1 = __builtin_amdgcn_mfma_f32_16x16x32_bf16(fr.h, brow1, s_acc1, 0, 0, 0);
    }
    __syncthreads();   // all waves done reading hs_s -> reuse as S0

    // ---- S store: each wave writes its COMPLETE rows (no reduce) ----
    #pragma unroll
    for (int r = 0; r < 4; ++r) {
        S0[(w * 16 + quad * 4 + r) * 36 +  0 + l15] = s_acc0[r];
        S0[(w * 16 + quad * 4 + r) * 36 + 16 + l15] = s_acc1[r];
    }
    __syncthreads();

    // ---- per-edge logits + group-of-16 softmax ----
    float lg[4];
    #pragma unroll
    for (int j = 0; j < 4; ++j)
        lg[j] = S0[soff[j]];

    float mx = fmaxf(fmaxf(lg[0], lg[1]), fmaxf(lg[2], lg[3]));
    mx = fmaxf(mx, __shfl_xor(mx, 1));
    mx = fmaxf(mx, __shfl_xor(mx, 2));
    float ex[4], sm = 0.f;
    #pragma unroll
    for (int j = 0; j < 4; ++j) { ex[j] = __expf(lg[j] - mx); sm += ex[j]; }
    sm += __shfl_xor(sm, 1);
    sm += __shfl_xor(sm, 2);
    const float inv = 1.0f / sm;

    if (USE_WS) {
        float4 o = make_float4(ex[0] * inv, ex[1] * inv, ex[2] * inv, ex[3] * inv);
        *(float4*)(probs_or_out + (size_t)bl * 1024 + e0) = o;
    } else {
        const float skip = skipp[0];
        const float om = 1.0f - skip;
        #pragma unroll
        for (int j = 0; j < 4; ++j) {
            float g = fmaf(skip, ew[be0 + j], om * (ex[j] * inv));
            probs_or_out[(size_t)(be0 + j) * Lv + l] = g;
        }
    }
}

// ---------------------------------------------------------------------------
// Output kernel: tiled transpose of probs (b,l,e) -> ew_out (be,l), plus ei
// broadcast. Block = (lt, et, b) transposes one 64x64 tile.
// ---------------------------------------------------------------------------
__global__ __launch_bounds__(256) void output_kernel(
    const float* __restrict__ probs, const int* __restrict__ eidx,
    const float* __restrict__ ew, const float* __restrict__ skipp,
    float* __restrict__ out)
{
    __shared__ float tile[64 * 68];
    const int lt = blockIdx.x;   // 0..15
    const int et = blockIdx.y;   // 0..15
    const int b  = blockIdx.z;   // 0..3
    const int t  = threadIdx.x;
    const int tr = t >> 4;       // 0..15
    const int tc = t & 15;       // 0..15

    #pragma unroll
    for (int q = 0; q < 4; ++q) {
        const int lloc = q * 16 + tr;
        float4 v = *(const float4*)(probs +
            ((size_t)(b * 1024 + lt * 64 + lloc)) * 1024 + et * 64 + tc * 4);
        *(float4*)(&tile[lloc * 68 + tc * 4]) = v;
    }
    __syncthreads();

    const float skip = skipp[0];
    const float om = 1.0f - skip;
    float* out_ei0 = out;
    float* out_ei1 = out + EI_PLANE;
    float* out_ew  = out + 2 * EI_PLANE;

    #pragma unroll
    for (int q = 0; q < 4; ++q) {
        const int eloc = q * 16 + tr;
        const int be = b * Ev + et * 64 + eloc;
        const float w  = ew[be];
        const float sv = (float)eidx[be];
        const float dv = (float)eidx[BE + be];
        const int lloc0 = tc * 4;
        float4 o;
        o.x = fmaf(skip, w, om * tile[(lloc0 + 0) * 68 + eloc]);
        o.y = fmaf(skip, w, om * tile[(lloc0 + 1) * 68 + eloc]);
        o.z = fmaf(skip, w, om * tile[(lloc0 + 2) * 68 + eloc]);
        o.w = fmaf(skip, w, om * tile[(lloc0 + 3) * 68 + eloc]);
        const size_t off = (size_t)be * Lv + lt * 64 + lloc0;
        *(float4*)(out_ew  + off) = o;
        *(float4*)(out_ei0 + off) = make_float4(sv, sv, sv, sv);
        *(float4*)(out_ei1 + off) = make_float4(dv, dv, dv, dv);
    }
}

// Fallback ei broadcast kernel (only used if ws too small for probs buffer)
__global__ __launch_bounds__(256) void ei_kernel(
    const int* __restrict__ eidx, float* __restrict__ out)
{
    const int blk = blockIdx.x;            // 0..8191  (c*4096 + j)
    const int c = blk >> 12;
    const int j = blk & 4095;
    const float v = (float)eidx[c * BE + j];
    float4 o = make_float4(v, v, v, v);
    *(float4*)(out + (size_t)blk * 1024 + threadIdx.x * 4) = o;
}

// ---------------------------------------------------------------------------
extern "C" void kernel_launch(void* const* d_in, const int* in_sizes, int n_in,
                              void* d_out, int out_size, void* d_ws, size_t ws_size,
                              hipStream_t stream)
{
    const float* hs   = (const float*)d_in[0];
    const int*   eidx = (const int*)d_in[1];
    const float* ew   = (const float*)d_in[2];
    const float* Wq   = (const float*)d_in[3];
    const float* bq   = (const float*)d_in[4];
    const float* Wk   = (const float*)d_in[5];
    // d_in[6] = bk: provably unused (cancels in softmax)
    const float* skip = (const float*)d_in[7];

    char* wsb = (char*)d_ws;
    __bf16* Mb   = (__bf16*)wsb;                       // 65536 bf16 = 128 KiB
    float*  rv   = (float*)(wsb + 131072);             // 256 fp32 = 1 KiB
    float*  probs = (float*)(wsb + 132096);            // 4M fp32 = 16 MiB
    const size_t need = 132096 + (size_t)Bv * Lv * Ev * sizeof(float);

    precompute_kernel<<<dim3(257), dim3(256), 0, stream>>>(Wq, Wk, bq, Mb, rv);

    if (ws_size >= need) {
        edge_main<true><<<dim3(Bv * Lv), dim3(256), 0, stream>>>(
            hs, eidx, ew, skip, Mb, rv, probs);
        output_kernel<<<dim3(16, 16, 4), dim3(256), 0, stream>>>(
            probs, eidx, ew, skip, (float*)d_out);
    } else {
        float* out_ew = (float*)d_out + 2 * EI_PLANE;
        edge_main<false><<<dim3(Bv * Lv), dim3(256), 0, stream>>>(
            hs, eidx, ew, skip, Mb, rv, out_ew);
        ei_kernel<<<dim3(2 * BE), dim3(256), 0, stream>>>(eidx, (float*)d_out);
    }
}